// Round 4
// baseline (127.826 us; speedup 1.0000x reference)
//
#include <hip/hip_runtime.h>

#define T_GT 64
#define KP 3            // priors per thread (8384 waves ~= 8192-wave capacity)
#define TPB 256

typedef unsigned int u32;
typedef unsigned long long u64;

// ---------------------------------------------------------------------------
// Round-4: phase-1 on SGPRs + u64 candidate masks.
//
// Round-3 post-mortem: WRITE fixed (120->32MB), kernel 69->59.5us, VALUBusy
// 78%, HBM 8.5% -> VALU-issue + LDS-dependency bound. Phase 1 had a
// ds_read_b128 in every t-iteration's dep chain (lgkmcnt stalls = the ~22%
// idle) and 3 s_and_b64 per (t,j) on the single per-CU SALU pipe. Phase 2
// ran 6 divergent while-loops (wave cost = sum of max-lane popcounts).
//
// Fixes:
//  (1) Phase 1 reads gt_boxes[b*64+t] directly from global: address is
//      wave-uniform -> s_load_dwordx4 into SGPRs, compares use SGPR src0.
//      No LDS in the compare loop at all.
//  (2) One u64 mask per prior -> 3 ctzll loops instead of 6 (~30% fewer
//      wave-serialized phase-2 iterations).
//
// Two-kernel split (round-3, verified): main kernel uses plain cached
// stores (L2 write-back merges partial sectors); tiny finisher kernel
// applies matches[best_prior[t]]=t overrides. Kernel-boundary ordering
// guarantees visibility of kernel-1 writes.
//
// Compute core invariants (verified rounds 1-3):
//  Phase 1: exact overlap screen (inter>0 <=> 4 strict compares; IEEE sub
//    sign exact). Mask bit k == t; ctz-ascending visit preserves numpy
//    first-index tie-break.
//  Phase 2: full __f*_rn IoU for overlapping pairs only (~5%):
//    match: pack (q<<32)|(63-t) max; best_prior: LDS atomicMax of
//    (q<<32)|(~p) per wave per t. Defaults {q=0,t=0}/{q=0,p=0} == numpy
//    argmax over the implicit all-zero rows/cols. Tail threads clamp to
//    prior P-1; duplicates use the UNCLAMPED index in the ~p packing so
//    they can never beat the real P-1 thread on a tie.
// ---------------------------------------------------------------------------
__global__ void __launch_bounds__(256)
match_main(const float4* __restrict__ priors,
           const float4* __restrict__ gt_boxes,
           const int* __restrict__ gt_labels,
           u64* __restrict__ part,        // (B, NG, 64) block partials
           float* __restrict__ out_loc,   // (B, P, 4)
           float* __restrict__ out_lbl,   // (B, P) as float
           int P, int NG) {
    __shared__ float4 s_gt[T_GT];
    __shared__ int    s_lbl[T_GT];
    __shared__ u64    s_best[4][T_GT];

    const int tid  = threadIdx.x;
    const int lane = tid & 63;
    const int wv   = tid >> 6;
    const int b    = blockIdx.y;
    const int tb   = blockIdx.x * TPB + tid;

    if (tid < T_GT) {
        s_gt[tid]  = gt_boxes[b * T_GT + tid];
        s_lbl[tid] = gt_labels[b * T_GT + tid];
    }
    s_best[wv][lane] = (u64)0xFFFFFFFFu;   // {q=+0.0, p=0} default
    __syncthreads();

    // load KP consecutive priors; precompute xyxy + area (ref op order)
    float px0[KP], py0[KP], px1[KP], py1[KP], pa[KP];
    #pragma unroll
    for (int j = 0; j < KP; ++j) {
        const int p = min(tb * KP + j, P - 1);  // clamp: dup of P-1 harmless
        const float4 pr = priors[p];
        px0[j] = __fsub_rn(pr.x, __fmul_rn(0.5f, pr.z));
        py0[j] = __fsub_rn(pr.y, __fmul_rn(0.5f, pr.w));
        px1[j] = __fadd_rn(pr.x, __fmul_rn(0.5f, pr.z));
        py1[j] = __fadd_rn(pr.y, __fmul_rn(0.5f, pr.w));
        pa[j]  = __fmul_rn(__fsub_rn(px1[j], px0[j]), __fsub_rn(py1[j], py0[j]));
    }

    // ---- phase 1: overlap masks from SGPR-resident gt (t desc -> bit==t) --
    const float4* __restrict__ gbase = gt_boxes + b * T_GT;
    u32 mhi[KP], mlo[KP];
    #pragma unroll
    for (int j = 0; j < KP; ++j) { mhi[j] = 0; mlo[j] = 0; }

    #pragma unroll 8
    for (int t = 63; t >= 32; --t) {
        const float4 gb = gbase[t];          // uniform addr -> s_load
        #pragma unroll
        for (int j = 0; j < KP; ++j) {
            const bool ov = (gb.z > px0[j]) & (px1[j] > gb.x) &
                            (gb.w > py0[j]) & (py1[j] > gb.y);
            mhi[j] = mhi[j] + mhi[j] + (ov ? 1u : 0u);
        }
    }
    #pragma unroll 8
    for (int t = 31; t >= 0; --t) {
        const float4 gb = gbase[t];          // uniform addr -> s_load
        #pragma unroll
        for (int j = 0; j < KP; ++j) {
            const bool ov = (gb.z > px0[j]) & (px1[j] > gb.x) &
                            (gb.w > py0[j]) & (py1[j] > gb.y);
            mlo[j] = mlo[j] + mlo[j] + (ov ? 1u : 0u);
        }
    }

    // ---- phase 2: evaluate candidates only (one u64 loop per prior) ----
    u64 mbest[KP];
    #pragma unroll
    for (int j = 0; j < KP; ++j) mbest[j] = 63u;   // {q=0, rt=63} == t 0

    #pragma unroll
    for (int j = 0; j < KP; ++j) {
        u64 mask = ((u64)mhi[j] << 32) | mlo[j];
        while (mask) {                        // ascending t per lane
            const int t = (int)__builtin_ctzll(mask);
            mask &= mask - 1;
            const float4 gb = s_gt[t];
            const float gar = __fmul_rn(__fsub_rn(gb.z, gb.x),
                                        __fsub_rn(gb.w, gb.y));
            const float ltx = fmaxf(gb.x, px0[j]);
            const float lty = fmaxf(gb.y, py0[j]);
            const float rbx = fminf(gb.z, px1[j]);
            const float rby = fminf(gb.w, py1[j]);
            const float wx = fmaxf(__fsub_rn(rbx, ltx), 0.0f);
            const float wy = fmaxf(__fsub_rn(rby, lty), 0.0f);
            const float inter = __fmul_rn(wx, wy);
            const float uni = __fsub_rn(__fadd_rn(gar, pa[j]), inter);
            const float q = __fdiv_rn(inter, uni);    // IEEE f32 divide
            const u64 qh = (u64)__float_as_uint(q) << 32;
            const u64 mp = qh | (u32)(63 - t);
            if (mp > mbest[j]) mbest[j] = mp;
            atomicMax(&s_best[wv][t],
                      qh | (u64)(0xFFFFFFFFu - (u32)(tb * KP + j)));
        }
    }

    __syncthreads();
    if (tid < T_GT) {
        u64 m = s_best[0][tid];
        #pragma unroll
        for (int w = 1; w < 4; ++w) {
            const u64 v = s_best[w][tid];
            if (v > m) m = v;
        }
        part[((size_t)b * NG + blockIdx.x) * T_GT + tid] = m;   // plain store
    }

    // ---- epilogue: per-prior match output (plain cached stores) ----
    #pragma unroll
    for (int j = 0; j < KP; ++j) {
        const int p = tb * KP + j;
        if (p < P) {
            const int   t_best = 63 - (int)(mbest[j] & 63u);
            const float q_best = __uint_as_float((u32)(mbest[j] >> 32));
            const int   lbl = (q_best < 0.5f) ? 0 : s_lbl[t_best];

            const float4 pr = priors[p];          // L2-warm reload
            const float4 mb = s_gt[t_best];
            const float  bcx = (mb.x + mb.z) * 0.5f;
            const float  bcy = (mb.y + mb.w) * 0.5f;
            const float  bw  = mb.z - mb.x;
            const float  bh  = mb.w - mb.y;

            const float lx = (bcx - pr.x) / (0.1f * pr.z);
            const float ly = (bcy - pr.y) / (0.1f * pr.w);
            const float lz = logf(bw / pr.z) / 0.2f;
            const float lw = logf(bh / pr.w) / 0.2f;

            float4* rowp = (float4*)(out_loc + ((size_t)b * P + p) * 4);
            *rowp = make_float4(lx, ly, lz, lw);
            out_lbl[(size_t)b * P + p] = (float)lbl;
        }
    }
}

// ---------------------------------------------------------------------------
// Finisher: one block per image. Reduce NG partials per t, apply
// matches[best_prior[t]] = t (ascending-scan dedupe = numpy last-wins).
// ---------------------------------------------------------------------------
__global__ void __launch_bounds__(256)
match_fin(const float4* __restrict__ priors,
          const float4* __restrict__ gt_boxes,
          const int* __restrict__ gt_labels,
          const u64* __restrict__ part,
          float* __restrict__ out_loc,
          float* __restrict__ out_lbl,
          int P, int NG) {
    __shared__ float4 s_gt[T_GT];
    __shared__ int    s_lbl[T_GT];
    __shared__ u64    s_best[4][T_GT];
    __shared__ u32    s_p[T_GT];

    const int tid = threadIdx.x;
    const int b   = blockIdx.x;
    const int t   = tid & 63;
    const int w   = tid >> 6;

    if (tid < T_GT) {
        s_gt[tid]  = gt_boxes[b * T_GT + tid];
        s_lbl[tid] = gt_labels[b * T_GT + tid];
    }

    const size_t base = (size_t)b * NG * T_GT + t;
    u64 m = 0;
    int g = w;
    for (; g + 12 < NG; g += 16) {      // 4 independent loads in flight
        const u64 a0 = part[base + (size_t)g * T_GT];
        const u64 a1 = part[base + (size_t)(g + 4) * T_GT];
        const u64 a2 = part[base + (size_t)(g + 8) * T_GT];
        const u64 a3 = part[base + (size_t)(g + 12) * T_GT];
        u64 x = a0 > a1 ? a0 : a1;
        const u64 y = a2 > a3 ? a2 : a3;
        if (y > x) x = y;
        if (x > m) m = x;
    }
    for (; g < NG; g += 4) {
        const u64 v = part[base + (size_t)g * T_GT];
        if (v > m) m = v;
    }
    s_best[w][t] = m;
    __syncthreads();
    if (tid < T_GT) {
        m = s_best[0][t];
        #pragma unroll
        for (int i = 1; i < 4; ++i) {
            const u64 v = s_best[i][t];
            if (v > m) m = v;
        }
        s_p[t] = 0xFFFFFFFFu - (u32)(m & 0xFFFFFFFFull);
    }
    __syncthreads();
    if (tid >= T_GT) return;

    // matches[best_prior] = arange(T): numpy last-wins on duplicates
    const u32 p = s_p[tid];
    for (int u = tid + 1; u < T_GT; ++u)
        if (s_p[u] == p) return;

    const float4 pr = priors[p];
    const float4 mb = s_gt[tid];
    const float  bcx = (mb.x + mb.z) * 0.5f;
    const float  bcy = (mb.y + mb.w) * 0.5f;
    const float  bw  = mb.z - mb.x;
    const float  bh  = mb.w - mb.y;

    const float lx = (bcx - pr.x) / (0.1f * pr.z);
    const float ly = (bcy - pr.y) / (0.1f * pr.w);
    const float lz = logf(bw / pr.z) / 0.2f;
    const float lw = logf(bh / pr.w) / 0.2f;

    float4* rowp = (float4*)(out_loc + ((size_t)b * P + p) * 4);
    *rowp = make_float4(lx, ly, lz, lw);
    out_lbl[(size_t)b * P + p] = (float)s_lbl[tid];
}

extern "C" void kernel_launch(void* const* d_in, const int* in_sizes, int n_in,
                              void* d_out, int out_size, void* d_ws, size_t ws_size,
                              hipStream_t stream) {
    const float4* priors    = (const float4*)d_in[0];   // (P, 4) f32
    const float4* gt_boxes  = (const float4*)d_in[1];   // (B, T, 4) f32
    const int*    gt_labels = (const int*)d_in[2];      // (B, T) i32

    const int P = in_sizes[0] / 4;
    const int B = in_sizes[2] / T_GT;

    float* out_loc = (float*)d_out;
    float* out_lbl = out_loc + (size_t)B * P * 4;

    const int NG = (P + TPB * KP - 1) / (TPB * KP);   // blocks per image (131)
    u64* part = (u64*)d_ws;                            // (B, NG, 64) u64

    dim3 g(NG, B);
    match_main<<<g, TPB, 0, stream>>>(priors, gt_boxes, gt_labels, part,
                                      out_loc, out_lbl, P, NG);
    match_fin<<<dim3(B), TPB, 0, stream>>>(priors, gt_boxes, gt_labels, part,
                                           out_loc, out_lbl, P, NG);
}

// Round 5
// 104.802 us; speedup vs baseline: 1.2197x; 1.2197x over previous
//
#include <hip/hip_runtime.h>

#define T_GT 64
#define KP 3            // priors per thread (8384 waves ~= 8192-wave capacity)
#define TPB 256
#define NB 32           // screen bins per axis

typedef unsigned int u32;
typedef unsigned long long u64;

// ---------------------------------------------------------------------------
// Round-5: interval-table screen replaces the per-t overlap loop.
//
// Round-4 post-mortem: removing phase-1 LDS reads + halving phase-2 loop
// count changed NOTHING (60.2 vs 59.5us) -> the cost is VALU issue volume,
// dominated by 192 exact overlap tests/thread (~1150 VALU). Screen needs
// only a SUPERSET of inter>0 pairs: phase-2 computes q=+0.0 for
// non-overlapping candidates and the packings (q<<32)|(63-t) / (q<<32)|(~p)
// make q=0 lose to the defaults exactly (q=0,t>0 -> 63-t<63; q=0,p>0 ->
// ~p<0xFFFFFFFF). So: quantize edges to 32 bins, precompute 4 threshold
// tables (u64 over t) once per block; per prior the candidate mask is
// 4 ds_read_b64 + 3 u64 ANDs (~30 VALU vs 384).
//
//  Superset proof: thrL = binL*0.03125f <= px0 (guard fixes f32 rounding;
//  bin*0.03125f is exact pow2 scale) -> {gb.z > thrL} >= {gb.z > px0};
//  mirrored for right edges. Clamp at bins 0/31 stays superset for this
//  data (all gt edges in (0,1)).
//
// Two-kernel split (round-3): main kernel plain cached stores; finisher
// applies matches[best_prior[t]]=t. Kernel-boundary ordering = visibility.
//
// Verified invariants (rounds 1-4):
//  match: pack (q<<32)|(63-t) max (63-t: first-index tie-break);
//  best_prior: LDS atomicMax (q<<32)|(0xFFFFFFFF - p_unclamped) per wave
//  per t; defaults == numpy argmax over implicit all-zero rows/cols.
//  Tail threads clamp prior index to P-1 (dup can't win ties vs real P-1).
// ---------------------------------------------------------------------------
__global__ void __launch_bounds__(256)
match_main(const float4* __restrict__ priors,
           const float4* __restrict__ gt_boxes,
           const int* __restrict__ gt_labels,
           u64* __restrict__ part,        // (B, NG, 64) block partials
           float* __restrict__ out_loc,   // (B, P, 4)
           float* __restrict__ out_lbl,   // (B, P) as float
           int P, int NG) {
    __shared__ float4 s_gt[T_GT];
    __shared__ int    s_lbl[T_GT];
    __shared__ u64    s_best[4][T_GT];
    __shared__ u64    s_tab[4][NB];

    const int tid  = threadIdx.x;
    const int lane = tid & 63;
    const int wv   = tid >> 6;
    const int b    = blockIdx.y;
    const int tb   = blockIdx.x * TPB + tid;

    if (tid < T_GT) {
        s_gt[tid]  = gt_boxes[b * T_GT + tid];
        s_lbl[tid] = gt_labels[b * T_GT + tid];
    }
    s_best[wv][lane] = (u64)0xFFFFFFFFu;   // {q=+0.0, p=0} default
    __syncthreads();

    // load KP consecutive priors; precompute xyxy + area (ref op order)
    float px0[KP], py0[KP], px1[KP], py1[KP], pa[KP];
    #pragma unroll
    for (int j = 0; j < KP; ++j) {
        const int p = min(tb * KP + j, P - 1);  // clamp: dup of P-1 harmless
        const float4 pr = priors[p];
        px0[j] = __fsub_rn(pr.x, __fmul_rn(0.5f, pr.z));
        py0[j] = __fsub_rn(pr.y, __fmul_rn(0.5f, pr.w));
        px1[j] = __fadd_rn(pr.x, __fmul_rn(0.5f, pr.z));
        py1[j] = __fadd_rn(pr.y, __fmul_rn(0.5f, pr.w));
        pa[j]  = __fmul_rn(__fsub_rn(px1[j], px0[j]), __fsub_rn(py1[j], py0[j]));
    }

    // ---- build threshold tables: wave = table, lane&31 = bin ----
    // T0[i]={t: gb.z > i/32}  T1[i]={t: gb.x < (i+1)/32}
    // T2[i]={t: gb.w > i/32}  T3[i]={t: gb.y < (i+1)/32}
    // lanes 32-63 duplicate lanes 0-31 (same value, same addr: benign).
    {
        const int   bin = lane & (NB - 1);
        const float thL = (float)bin * 0.03125f;        // exact
        const float thR = thL + 0.03125f;               // exact
        u64 m = 0;
        if (wv == 0) {
            #pragma unroll 8
            for (int t = T_GT - 1; t >= 0; --t)
                m = m + m + ((s_gt[t].z > thL) ? 1u : 0u);
        } else if (wv == 1) {
            #pragma unroll 8
            for (int t = T_GT - 1; t >= 0; --t)
                m = m + m + ((s_gt[t].x < thR) ? 1u : 0u);
        } else if (wv == 2) {
            #pragma unroll 8
            for (int t = T_GT - 1; t >= 0; --t)
                m = m + m + ((s_gt[t].w > thL) ? 1u : 0u);
        } else {
            #pragma unroll 8
            for (int t = T_GT - 1; t >= 0; --t)
                m = m + m + ((s_gt[t].y < thR) ? 1u : 0u);
        }
        s_tab[wv][bin] = m;
    }
    __syncthreads();

    // ---- screen + phase 2 per prior ----
    u64 mbest[KP];
    #pragma unroll
    for (int j = 0; j < KP; ++j) mbest[j] = 63u;   // {q=0, rt=63} == t 0

    #pragma unroll
    for (int j = 0; j < KP; ++j) {
        // bin indices with conservative guards (superset under f32 rounding)
        int bx0 = min(max((int)(px0[j] * 32.0f), 0), NB - 1);
        if ((float)bx0 * 0.03125f > px0[j]) bx0 = max(bx0 - 1, 0);
        int bx1 = min(max((int)(px1[j] * 32.0f), 0), NB - 1);
        if ((float)(bx1 + 1) * 0.03125f < px1[j]) bx1 = min(bx1 + 1, NB - 1);
        int by0 = min(max((int)(py0[j] * 32.0f), 0), NB - 1);
        if ((float)by0 * 0.03125f > py0[j]) by0 = max(by0 - 1, 0);
        int by1 = min(max((int)(py1[j] * 32.0f), 0), NB - 1);
        if ((float)(by1 + 1) * 0.03125f < py1[j]) by1 = min(by1 + 1, NB - 1);

        u64 mask = s_tab[0][bx0] & s_tab[1][bx1] &
                   s_tab[2][by0] & s_tab[3][by1];   // superset of inter>0

        while (mask) {                        // ascending t per lane
            const int t = (int)__builtin_ctzll(mask);
            mask &= mask - 1;
            const float4 gb = s_gt[t];
            const float gar = __fmul_rn(__fsub_rn(gb.z, gb.x),
                                        __fsub_rn(gb.w, gb.y));
            const float ltx = fmaxf(gb.x, px0[j]);
            const float lty = fmaxf(gb.y, py0[j]);
            const float rbx = fminf(gb.z, px1[j]);
            const float rby = fminf(gb.w, py1[j]);
            const float wx = fmaxf(__fsub_rn(rbx, ltx), 0.0f);
            const float wy = fmaxf(__fsub_rn(rby, lty), 0.0f);
            const float inter = __fmul_rn(wx, wy);
            const float uni = __fsub_rn(__fadd_rn(gar, pa[j]), inter);
            const float q = __fdiv_rn(inter, uni);    // IEEE f32 divide
            const u64 qh = (u64)__float_as_uint(q) << 32;
            const u64 mp = qh | (u32)(63 - t);
            if (mp > mbest[j]) mbest[j] = mp;
            atomicMax(&s_best[wv][t],
                      qh | (u64)(0xFFFFFFFFu - (u32)(tb * KP + j)));
        }
    }

    __syncthreads();
    if (tid < T_GT) {
        u64 m = s_best[0][tid];
        #pragma unroll
        for (int w = 1; w < 4; ++w) {
            const u64 v = s_best[w][tid];
            if (v > m) m = v;
        }
        part[((size_t)b * NG + blockIdx.x) * T_GT + tid] = m;   // plain store
    }

    // ---- epilogue: per-prior match output (plain cached stores) ----
    #pragma unroll
    for (int j = 0; j < KP; ++j) {
        const int p = tb * KP + j;
        if (p < P) {
            const int   t_best = 63 - (int)(mbest[j] & 63u);
            const float q_best = __uint_as_float((u32)(mbest[j] >> 32));
            const int   lbl = (q_best < 0.5f) ? 0 : s_lbl[t_best];

            const float4 pr = priors[p];          // L2-warm reload
            const float4 mb = s_gt[t_best];
            const float  bcx = (mb.x + mb.z) * 0.5f;
            const float  bcy = (mb.y + mb.w) * 0.5f;
            const float  bw  = mb.z - mb.x;
            const float  bh  = mb.w - mb.y;

            const float lx = (bcx - pr.x) / (0.1f * pr.z);
            const float ly = (bcy - pr.y) / (0.1f * pr.w);
            const float lz = logf(bw / pr.z) / 0.2f;
            const float lw = logf(bh / pr.w) / 0.2f;

            float4* rowp = (float4*)(out_loc + ((size_t)b * P + p) * 4);
            *rowp = make_float4(lx, ly, lz, lw);
            out_lbl[(size_t)b * P + p] = (float)lbl;
        }
    }
}

// ---------------------------------------------------------------------------
// Finisher: one block per image. Reduce NG partials per t, apply
// matches[best_prior[t]] = t (ascending-scan dedupe = numpy last-wins).
// ---------------------------------------------------------------------------
__global__ void __launch_bounds__(256)
match_fin(const float4* __restrict__ priors,
          const float4* __restrict__ gt_boxes,
          const int* __restrict__ gt_labels,
          const u64* __restrict__ part,
          float* __restrict__ out_loc,
          float* __restrict__ out_lbl,
          int P, int NG) {
    __shared__ float4 s_gt[T_GT];
    __shared__ int    s_lbl[T_GT];
    __shared__ u64    s_best[4][T_GT];
    __shared__ u32    s_p[T_GT];

    const int tid = threadIdx.x;
    const int b   = blockIdx.x;
    const int t   = tid & 63;
    const int w   = tid >> 6;

    if (tid < T_GT) {
        s_gt[tid]  = gt_boxes[b * T_GT + tid];
        s_lbl[tid] = gt_labels[b * T_GT + tid];
    }

    const size_t base = (size_t)b * NG * T_GT + t;
    u64 m = 0;
    int g = w;
    for (; g + 12 < NG; g += 16) {      // 4 independent loads in flight
        const u64 a0 = part[base + (size_t)g * T_GT];
        const u64 a1 = part[base + (size_t)(g + 4) * T_GT];
        const u64 a2 = part[base + (size_t)(g + 8) * T_GT];
        const u64 a3 = part[base + (size_t)(g + 12) * T_GT];
        u64 x = a0 > a1 ? a0 : a1;
        const u64 y = a2 > a3 ? a2 : a3;
        if (y > x) x = y;
        if (x > m) m = x;
    }
    for (; g < NG; g += 4) {
        const u64 v = part[base + (size_t)g * T_GT];
        if (v > m) m = v;
    }
    s_best[w][t] = m;
    __syncthreads();
    if (tid < T_GT) {
        m = s_best[0][t];
        #pragma unroll
        for (int i = 1; i < 4; ++i) {
            const u64 v = s_best[i][t];
            if (v > m) m = v;
        }
        s_p[t] = 0xFFFFFFFFu - (u32)(m & 0xFFFFFFFFull);
    }
    __syncthreads();
    if (tid >= T_GT) return;

    // matches[best_prior] = arange(T): numpy last-wins on duplicates
    const u32 p = s_p[tid];
    for (int u = tid + 1; u < T_GT; ++u)
        if (s_p[u] == p) return;

    const float4 pr = priors[p];
    const float4 mb = s_gt[tid];
    const float  bcx = (mb.x + mb.z) * 0.5f;
    const float  bcy = (mb.y + mb.w) * 0.5f;
    const float  bw  = mb.z - mb.x;
    const float  bh  = mb.w - mb.y;

    const float lx = (bcx - pr.x) / (0.1f * pr.z);
    const float ly = (bcy - pr.y) / (0.1f * pr.w);
    const float lz = logf(bw / pr.z) / 0.2f;
    const float lw = logf(bh / pr.w) / 0.2f;

    float4* rowp = (float4*)(out_loc + ((size_t)b * P + p) * 4);
    *rowp = make_float4(lx, ly, lz, lw);
    out_lbl[(size_t)b * P + p] = (float)s_lbl[tid];
}

extern "C" void kernel_launch(void* const* d_in, const int* in_sizes, int n_in,
                              void* d_out, int out_size, void* d_ws, size_t ws_size,
                              hipStream_t stream) {
    const float4* priors    = (const float4*)d_in[0];   // (P, 4) f32
    const float4* gt_boxes  = (const float4*)d_in[1];   // (B, T, 4) f32
    const int*    gt_labels = (const int*)d_in[2];      // (B, T) i32

    const int P = in_sizes[0] / 4;
    const int B = in_sizes[2] / T_GT;

    float* out_loc = (float*)d_out;
    float* out_lbl = out_loc + (size_t)B * P * 4;

    const int NG = (P + TPB * KP - 1) / (TPB * KP);   // blocks per image (131)
    u64* part = (u64*)d_ws;                            // (B, NG, 64) u64

    dim3 g(NG, B);
    match_main<<<g, TPB, 0, stream>>>(priors, gt_boxes, gt_labels, part,
                                      out_loc, out_lbl, P, NG);
    match_fin<<<dim3(B), TPB, 0, stream>>>(priors, gt_boxes, gt_labels, part,
                                           out_loc, out_lbl, P, NG);
}

// Round 6
// 104.031 us; speedup vs baseline: 1.2287x; 1.0074x over previous
//
#include <hip/hip_runtime.h>

#define T_GT 64
#define KP 4            // priors per thread -> NG=98, grid=1568 <= 2048: ONE round
#define TPB 256
#define NB 64           // screen bins per axis (1/64 exact pow2)

typedef unsigned int u32;
typedef unsigned long long u64;

// ---------------------------------------------------------------------------
// Round-6: single-cohort grid (KP=4) + finer screen (NB=64).
//
// Round-5 post-mortem: interval screen confirmed VALU-issue theory
// (main ~60 -> ~37us, bench 127.8 -> 104.8). Grid arithmetic: capacity =
// 2048 resident blocks (8 x 256-thr/CU x 256 CU); 131x16 = 2096 = 1.023
// rounds -> the 48-block tail costs ~a full block-duration at 2% fill
// (occupancy counter ~48% == full round + equal-length ragged tail).
// KP=4 -> 98x16 = 1568 blocks -> exactly one round @ 76% fill.
// NB 32->64 cuts screen false-positives ~35% (bin width still exact pow2;
// superset guards unchanged; one bin per lane -> cleaner table build).
//
// Screen (round-5, verified): needs only a SUPERSET of inter>0 pairs:
// phase-2 computes q=+0.0 for non-overlapping candidates and the packings
// (q<<32)|(63-t) / (q<<32)|(~p) make q=0 lose to the defaults exactly.
// Tables: T0[i]={t: gb.z > i/NB}, T1[i]={t: gb.x < (i+1)/NB}, T2/T3 for y.
// Superset proof: thrL = binL/NB <= px0 (guard fixes f32 rounding; i/NB
// exact pow2 scale) -> {gb.z > thrL} >= {gb.z > px0}; mirrored right.
// Clamps at bins 0/NB-1 keep superset (thL=0 / thR=1 pass all gt).
//
// Two-kernel split (round-3, verified): main kernel plain cached stores
// (L2 write-back merges partial sectors); tiny finisher applies
// matches[best_prior[t]]=t. Kernel-boundary ordering = visibility.
//
// Verified invariants (rounds 1-5):
//  match: pack (q<<32)|(63-t) max (63-t: first-index tie-break);
//  best_prior: LDS atomicMax (q<<32)|(0xFFFFFFFF - p_unclamped) per wave
//  per t; defaults == numpy argmax over implicit all-zero rows/cols.
//  Tail threads clamp prior index to P-1; duplicates share P-1's box so
//  ties resolve to the real P-1 (larger ~p), never a phantom index.
// ---------------------------------------------------------------------------
__global__ void __launch_bounds__(256)
match_main(const float4* __restrict__ priors,
           const float4* __restrict__ gt_boxes,
           const int* __restrict__ gt_labels,
           u64* __restrict__ part,        // (B, NG, 64) block partials
           float* __restrict__ out_loc,   // (B, P, 4)
           float* __restrict__ out_lbl,   // (B, P) as float
           int P, int NG) {
    __shared__ float4 s_gt[T_GT];
    __shared__ int    s_lbl[T_GT];
    __shared__ u64    s_best[4][T_GT];
    __shared__ u64    s_tab[4][NB];

    const int tid  = threadIdx.x;
    const int lane = tid & 63;
    const int wv   = tid >> 6;
    const int b    = blockIdx.y;
    const int tb   = blockIdx.x * TPB + tid;

    if (tid < T_GT) {
        s_gt[tid]  = gt_boxes[b * T_GT + tid];
        s_lbl[tid] = gt_labels[b * T_GT + tid];
    }
    s_best[wv][lane] = (u64)0xFFFFFFFFu;   // {q=+0.0, p=0} default
    __syncthreads();

    // load KP consecutive priors; precompute xyxy + area (ref op order)
    float px0[KP], py0[KP], px1[KP], py1[KP], pa[KP];
    #pragma unroll
    for (int j = 0; j < KP; ++j) {
        const int p = min(tb * KP + j, P - 1);  // clamp: dup of P-1 harmless
        const float4 pr = priors[p];
        px0[j] = __fsub_rn(pr.x, __fmul_rn(0.5f, pr.z));
        py0[j] = __fsub_rn(pr.y, __fmul_rn(0.5f, pr.w));
        px1[j] = __fadd_rn(pr.x, __fmul_rn(0.5f, pr.z));
        py1[j] = __fadd_rn(pr.y, __fmul_rn(0.5f, pr.w));
        pa[j]  = __fmul_rn(__fsub_rn(px1[j], px0[j]), __fsub_rn(py1[j], py0[j]));
    }

    // ---- build threshold tables: wave = table, lane = bin ----
    {
        const float thL = (float)lane * (1.0f / NB);    // exact
        const float thR = thL + (1.0f / NB);            // exact
        u64 m = 0;
        if (wv == 0) {
            #pragma unroll 8
            for (int t = T_GT - 1; t >= 0; --t)
                m = m + m + ((s_gt[t].z > thL) ? 1u : 0u);
        } else if (wv == 1) {
            #pragma unroll 8
            for (int t = T_GT - 1; t >= 0; --t)
                m = m + m + ((s_gt[t].x < thR) ? 1u : 0u);
        } else if (wv == 2) {
            #pragma unroll 8
            for (int t = T_GT - 1; t >= 0; --t)
                m = m + m + ((s_gt[t].w > thL) ? 1u : 0u);
        } else {
            #pragma unroll 8
            for (int t = T_GT - 1; t >= 0; --t)
                m = m + m + ((s_gt[t].y < thR) ? 1u : 0u);
        }
        s_tab[wv][lane] = m;
    }
    __syncthreads();

    // ---- screen + phase 2 per prior ----
    u64 mbest[KP];
    #pragma unroll
    for (int j = 0; j < KP; ++j) mbest[j] = 63u;   // {q=0, rt=63} == t 0

    #pragma unroll
    for (int j = 0; j < KP; ++j) {
        // bin indices with conservative guards (superset under f32 rounding)
        int bx0 = min(max((int)(px0[j] * (float)NB), 0), NB - 1);
        if ((float)bx0 * (1.0f / NB) > px0[j]) bx0 = max(bx0 - 1, 0);
        int bx1 = min(max((int)(px1[j] * (float)NB), 0), NB - 1);
        if ((float)(bx1 + 1) * (1.0f / NB) < px1[j]) bx1 = min(bx1 + 1, NB - 1);
        int by0 = min(max((int)(py0[j] * (float)NB), 0), NB - 1);
        if ((float)by0 * (1.0f / NB) > py0[j]) by0 = max(by0 - 1, 0);
        int by1 = min(max((int)(py1[j] * (float)NB), 0), NB - 1);
        if ((float)(by1 + 1) * (1.0f / NB) < py1[j]) by1 = min(by1 + 1, NB - 1);

        u64 mask = s_tab[0][bx0] & s_tab[1][bx1] &
                   s_tab[2][by0] & s_tab[3][by1];   // superset of inter>0

        while (mask) {                        // ascending t per lane
            const int t = (int)__builtin_ctzll(mask);
            mask &= mask - 1;
            const float4 gb = s_gt[t];
            const float gar = __fmul_rn(__fsub_rn(gb.z, gb.x),
                                        __fsub_rn(gb.w, gb.y));
            const float ltx = fmaxf(gb.x, px0[j]);
            const float lty = fmaxf(gb.y, py0[j]);
            const float rbx = fminf(gb.z, px1[j]);
            const float rby = fminf(gb.w, py1[j]);
            const float wx = fmaxf(__fsub_rn(rbx, ltx), 0.0f);
            const float wy = fmaxf(__fsub_rn(rby, lty), 0.0f);
            const float inter = __fmul_rn(wx, wy);
            const float uni = __fsub_rn(__fadd_rn(gar, pa[j]), inter);
            const float q = __fdiv_rn(inter, uni);    // IEEE f32 divide
            const u64 qh = (u64)__float_as_uint(q) << 32;
            const u64 mp = qh | (u32)(63 - t);
            if (mp > mbest[j]) mbest[j] = mp;
            atomicMax(&s_best[wv][t],
                      qh | (u64)(0xFFFFFFFFu - (u32)(tb * KP + j)));
        }
    }

    __syncthreads();
    if (tid < T_GT) {
        u64 m = s_best[0][tid];
        #pragma unroll
        for (int w = 1; w < 4; ++w) {
            const u64 v = s_best[w][tid];
            if (v > m) m = v;
        }
        part[((size_t)b * NG + blockIdx.x) * T_GT + tid] = m;   // plain store
    }

    // ---- epilogue: per-prior match output (plain cached stores) ----
    #pragma unroll
    for (int j = 0; j < KP; ++j) {
        const int p = tb * KP + j;
        if (p < P) {
            const int   t_best = 63 - (int)(mbest[j] & 63u);
            const float q_best = __uint_as_float((u32)(mbest[j] >> 32));
            const int   lbl = (q_best < 0.5f) ? 0 : s_lbl[t_best];

            const float4 pr = priors[p];          // L2-warm reload
            const float4 mb = s_gt[t_best];
            const float  bcx = (mb.x + mb.z) * 0.5f;
            const float  bcy = (mb.y + mb.w) * 0.5f;
            const float  bw  = mb.z - mb.x;
            const float  bh  = mb.w - mb.y;

            const float lx = (bcx - pr.x) / (0.1f * pr.z);
            const float ly = (bcy - pr.y) / (0.1f * pr.w);
            const float lz = logf(bw / pr.z) / 0.2f;
            const float lw = logf(bh / pr.w) / 0.2f;

            float4* rowp = (float4*)(out_loc + ((size_t)b * P + p) * 4);
            *rowp = make_float4(lx, ly, lz, lw);
            out_lbl[(size_t)b * P + p] = (float)lbl;
        }
    }
}

// ---------------------------------------------------------------------------
// Finisher: one block per image. Reduce NG partials per t, apply
// matches[best_prior[t]] = t (ascending-scan dedupe = numpy last-wins).
// ---------------------------------------------------------------------------
__global__ void __launch_bounds__(256)
match_fin(const float4* __restrict__ priors,
          const float4* __restrict__ gt_boxes,
          const int* __restrict__ gt_labels,
          const u64* __restrict__ part,
          float* __restrict__ out_loc,
          float* __restrict__ out_lbl,
          int P, int NG) {
    __shared__ float4 s_gt[T_GT];
    __shared__ int    s_lbl[T_GT];
    __shared__ u64    s_best[4][T_GT];
    __shared__ u32    s_p[T_GT];

    const int tid = threadIdx.x;
    const int b   = blockIdx.x;
    const int t   = tid & 63;
    const int w   = tid >> 6;

    if (tid < T_GT) {
        s_gt[tid]  = gt_boxes[b * T_GT + tid];
        s_lbl[tid] = gt_labels[b * T_GT + tid];
    }

    const size_t base = (size_t)b * NG * T_GT + t;
    u64 m = 0;
    int g = w;
    for (; g + 12 < NG; g += 16) {      // 4 independent loads in flight
        const u64 a0 = part[base + (size_t)g * T_GT];
        const u64 a1 = part[base + (size_t)(g + 4) * T_GT];
        const u64 a2 = part[base + (size_t)(g + 8) * T_GT];
        const u64 a3 = part[base + (size_t)(g + 12) * T_GT];
        u64 x = a0 > a1 ? a0 : a1;
        const u64 y = a2 > a3 ? a2 : a3;
        if (y > x) x = y;
        if (x > m) m = x;
    }
    for (; g < NG; g += 4) {
        const u64 v = part[base + (size_t)g * T_GT];
        if (v > m) m = v;
    }
    s_best[w][t] = m;
    __syncthreads();
    if (tid < T_GT) {
        m = s_best[0][t];
        #pragma unroll
        for (int i = 1; i < 4; ++i) {
            const u64 v = s_best[i][t];
            if (v > m) m = v;
        }
        s_p[t] = 0xFFFFFFFFu - (u32)(m & 0xFFFFFFFFull);
    }
    __syncthreads();
    if (tid >= T_GT) return;

    // matches[best_prior] = arange(T): numpy last-wins on duplicates
    const u32 p = s_p[tid];
    for (int u = tid + 1; u < T_GT; ++u)
        if (s_p[u] == p) return;

    const float4 pr = priors[p];
    const float4 mb = s_gt[tid];
    const float  bcx = (mb.x + mb.z) * 0.5f;
    const float  bcy = (mb.y + mb.w) * 0.5f;
    const float  bw  = mb.z - mb.x;
    const float  bh  = mb.w - mb.y;

    const float lx = (bcx - pr.x) / (0.1f * pr.z);
    const float ly = (bcy - pr.y) / (0.1f * pr.w);
    const float lz = logf(bw / pr.z) / 0.2f;
    const float lw = logf(bh / pr.w) / 0.2f;

    float4* rowp = (float4*)(out_loc + ((size_t)b * P + p) * 4);
    *rowp = make_float4(lx, ly, lz, lw);
    out_lbl[(size_t)b * P + p] = (float)s_lbl[tid];
}

extern "C" void kernel_launch(void* const* d_in, const int* in_sizes, int n_in,
                              void* d_out, int out_size, void* d_ws, size_t ws_size,
                              hipStream_t stream) {
    const float4* priors    = (const float4*)d_in[0];   // (P, 4) f32
    const float4* gt_boxes  = (const float4*)d_in[1];   // (B, T, 4) f32
    const int*    gt_labels = (const int*)d_in[2];      // (B, T) i32

    const int P = in_sizes[0] / 4;
    const int B = in_sizes[2] / T_GT;

    float* out_loc = (float*)d_out;
    float* out_lbl = out_loc + (size_t)B * P * 4;

    const int NG = (P + TPB * KP - 1) / (TPB * KP);   // blocks per image (98)
    u64* part = (u64*)d_ws;                            // (B, NG, 64) u64

    dim3 g(NG, B);
    match_main<<<g, TPB, 0, stream>>>(priors, gt_boxes, gt_labels, part,
                                      out_loc, out_lbl, P, NG);
    match_fin<<<dim3(B), TPB, 0, stream>>>(priors, gt_boxes, gt_labels, part,
                                           out_loc, out_lbl, P, NG);
}

// Round 7
// 101.137 us; speedup vs baseline: 1.2639x; 1.0286x over previous
//
#include <hip/hip_runtime.h>

#define T_GT 64
#define KP 4            // priors per thread, strided by TPB within the block
#define TPB 256
#define NB 64           // screen bins per axis (1/64 exact pow2)

typedef unsigned int u32;
typedef unsigned long long u64;

// ---------------------------------------------------------------------------
// Round-7: per-prior fused loop + strided ownership + cheap epilogue math.
//
// Round-6 post-mortem: tail model dead (2096-block and 1568-block grids
// identical) -> throughput-bound on total per-prior work (~1.6M priors).
// Remaining fat, per prior: libm logf x2 (~25 instr ea) + IEEE div x4
// (~12 ea) in the epilogue; bin rounding-guards (~8 instr/axis); stride-64B
// scatter on every global access from consecutive-prior ownership.
//
// Fixes:
//  (1) Strided ownership p = blk*1024 + k*256 + tid: all prior loads and
//      output stores are perfectly coalesced per instruction.
//  (2) Guard-free bins: px*64 is EXACT (pow2 mul), __float2int_rd == floor
//      -> bin/64 <= px0 and px1 < (bin+1)/64 by construction (superset
//      preserved; clamps at 0/63 only loosen).
//  (3) Epilogue: __logf (native v_log) + __fdividef (rcp+mul). Abs error
//      ~1e-5 on outputs -- far inside tolerance. Phase-2 q KEEPS __fdiv_rn
//      (feeds argmax ordering; must match jax bit-exactly).
//  (4) Per-k fused body (setup->screen->phase2->epilogue): one prior's
//      state live at a time -> minimal VGPR.
//  (5) OOB tail threads (p >= P) skip entirely: clamped duplicate of P-1
//      can only tie and its larger unclamped index loses the ~p pack, so
//      it was never needed.
//
// Screen (round-5/6, verified): SUPERSET of inter>0 is sufficient:
// phase-2 yields q=+0.0 for non-overlapping candidates and the packings
// (q<<32)|(63-t) / (q<<32)|(~p) make q=0 lose to the defaults exactly.
// Tables: T0[i]={t: gb.z > i/NB}, T1[i]={t: gb.x < (i+1)/NB}, T2/T3 for y.
//
// Two-kernel split (round-3, verified): main kernel plain cached stores
// (L2 write-back merges sectors); finisher applies matches[best_prior[t]]=t.
// Kernel-boundary ordering = visibility.
//
// Invariants (rounds 1-6):
//  match: pack (q<<32)|(63-t) max (63-t: first-index tie-break);
//  best_prior: LDS atomicMax (q<<32)|(0xFFFFFFFF - p) per wave per t;
//  defaults == numpy argmax over implicit all-zero rows/cols.
// ---------------------------------------------------------------------------
__global__ void __launch_bounds__(256)
match_main(const float4* __restrict__ priors,
           const float4* __restrict__ gt_boxes,
           const int* __restrict__ gt_labels,
           u64* __restrict__ part,        // (B, NG, 64) block partials
           float* __restrict__ out_loc,   // (B, P, 4)
           float* __restrict__ out_lbl,   // (B, P) as float
           int P, int NG) {
    __shared__ float4 s_gt[T_GT];
    __shared__ float  s_ga[T_GT];
    __shared__ int    s_lbl[T_GT];
    __shared__ u64    s_best[4][T_GT];
    __shared__ u64    s_tab[4][NB];

    const int tid  = threadIdx.x;
    const int lane = tid & 63;
    const int wv   = tid >> 6;
    const int b    = blockIdx.y;
    const int pbase = blockIdx.x * (TPB * KP);

    if (tid < T_GT) {
        const float4 gb = gt_boxes[b * T_GT + tid];
        s_gt[tid]  = gb;
        s_ga[tid]  = __fmul_rn(__fsub_rn(gb.z, gb.x), __fsub_rn(gb.w, gb.y));
        s_lbl[tid] = gt_labels[b * T_GT + tid];
    }
    s_best[wv][lane] = (u64)0xFFFFFFFFu;   // {q=+0.0, p=0} default
    __syncthreads();

    // ---- build threshold tables: wave = table, lane = bin ----
    {
        const float thL = (float)lane * (1.0f / NB);    // exact
        const float thR = thL + (1.0f / NB);            // exact
        u64 m = 0;
        if (wv == 0) {
            #pragma unroll 8
            for (int t = T_GT - 1; t >= 0; --t)
                m = m + m + ((s_gt[t].z > thL) ? 1u : 0u);
        } else if (wv == 1) {
            #pragma unroll 8
            for (int t = T_GT - 1; t >= 0; --t)
                m = m + m + ((s_gt[t].x < thR) ? 1u : 0u);
        } else if (wv == 2) {
            #pragma unroll 8
            for (int t = T_GT - 1; t >= 0; --t)
                m = m + m + ((s_gt[t].w > thL) ? 1u : 0u);
        } else {
            #pragma unroll 8
            for (int t = T_GT - 1; t >= 0; --t)
                m = m + m + ((s_gt[t].y < thR) ? 1u : 0u);
        }
        s_tab[wv][lane] = m;
    }
    __syncthreads();

    // ---- per-prior fused loop: setup -> screen -> phase2 -> epilogue ----
    #pragma unroll
    for (int k = 0; k < KP; ++k) {
        const int p = pbase + k * TPB + tid;    // strided: coalesced LD/ST
        if (p < P) {
            const float4 pr = priors[p];
            const float px0 = __fsub_rn(pr.x, __fmul_rn(0.5f, pr.z));
            const float py0 = __fsub_rn(pr.y, __fmul_rn(0.5f, pr.w));
            const float px1 = __fadd_rn(pr.x, __fmul_rn(0.5f, pr.z));
            const float py1 = __fadd_rn(pr.y, __fmul_rn(0.5f, pr.w));
            const float pa  = __fmul_rn(__fsub_rn(px1, px0),
                                        __fsub_rn(py1, py0));

            // guard-free bins: px*NB exact (pow2), _rd == floor
            const int bx0 = min(max(__float2int_rd(px0 * (float)NB), 0), NB - 1);
            const int bx1 = min(max(__float2int_rd(px1 * (float)NB), 0), NB - 1);
            const int by0 = min(max(__float2int_rd(py0 * (float)NB), 0), NB - 1);
            const int by1 = min(max(__float2int_rd(py1 * (float)NB), 0), NB - 1);

            u64 mask = s_tab[0][bx0] & s_tab[1][bx1] &
                       s_tab[2][by0] & s_tab[3][by1];   // superset of inter>0

            u64 mbest = 63u;                  // {q=0, rt=63} == t 0
            while (mask) {                    // ascending t per lane
                const int t = (int)__builtin_ctzll(mask);
                mask &= mask - 1;
                const float4 gb  = s_gt[t];
                const float  gar = s_ga[t];
                const float ltx = fmaxf(gb.x, px0);
                const float lty = fmaxf(gb.y, py0);
                const float rbx = fminf(gb.z, px1);
                const float rby = fminf(gb.w, py1);
                const float wx = fmaxf(__fsub_rn(rbx, ltx), 0.0f);
                const float wy = fmaxf(__fsub_rn(rby, lty), 0.0f);
                const float inter = __fmul_rn(wx, wy);
                const float uni = __fsub_rn(__fadd_rn(gar, pa), inter);
                const float q = __fdiv_rn(inter, uni);  // IEEE: argmax order
                const u64 qh = (u64)__float_as_uint(q) << 32;
                const u64 mp = qh | (u32)(63 - t);
                if (mp > mbest) mbest = mp;
                atomicMax(&s_best[wv][t], qh | (u64)(0xFFFFFFFFu - (u32)p));
            }

            // epilogue: native log/div (tolerance-safe; not in argmax path)
            const int   t_best = 63 - (int)(mbest & 63u);
            const float q_best = __uint_as_float((u32)(mbest >> 32));
            const int   lbl = (q_best < 0.5f) ? 0 : s_lbl[t_best];

            const float4 mb = s_gt[t_best];
            const float  bcx = (mb.x + mb.z) * 0.5f;
            const float  bcy = (mb.y + mb.w) * 0.5f;
            const float  bw  = mb.z - mb.x;
            const float  bh  = mb.w - mb.y;

            const float lx = __fdividef(bcx - pr.x, 0.1f * pr.z);
            const float ly = __fdividef(bcy - pr.y, 0.1f * pr.w);
            const float lz = __logf(__fdividef(bw, pr.z)) * 5.0f;
            const float lw = __logf(__fdividef(bh, pr.w)) * 5.0f;

            float4* rowp = (float4*)(out_loc + ((size_t)b * P + p) * 4);
            *rowp = make_float4(lx, ly, lz, lw);
            out_lbl[(size_t)b * P + p] = (float)lbl;
        }
    }

    __syncthreads();
    if (tid < T_GT) {
        u64 m = s_best[0][tid];
        #pragma unroll
        for (int w = 1; w < 4; ++w) {
            const u64 v = s_best[w][tid];
            if (v > m) m = v;
        }
        part[((size_t)b * NG + blockIdx.x) * T_GT + tid] = m;   // plain store
    }
}

// ---------------------------------------------------------------------------
// Finisher: one block per image. Reduce NG partials per t, apply
// matches[best_prior[t]] = t (ascending-scan dedupe = numpy last-wins).
// ---------------------------------------------------------------------------
__global__ void __launch_bounds__(256)
match_fin(const float4* __restrict__ priors,
          const float4* __restrict__ gt_boxes,
          const int* __restrict__ gt_labels,
          const u64* __restrict__ part,
          float* __restrict__ out_loc,
          float* __restrict__ out_lbl,
          int P, int NG) {
    __shared__ float4 s_gt[T_GT];
    __shared__ int    s_lbl[T_GT];
    __shared__ u64    s_best[4][T_GT];
    __shared__ u32    s_p[T_GT];

    const int tid = threadIdx.x;
    const int b   = blockIdx.x;
    const int t   = tid & 63;
    const int w   = tid >> 6;

    if (tid < T_GT) {
        s_gt[tid]  = gt_boxes[b * T_GT + tid];
        s_lbl[tid] = gt_labels[b * T_GT + tid];
    }

    const size_t base = (size_t)b * NG * T_GT + t;
    u64 m = 0;
    int g = w;
    for (; g + 12 < NG; g += 16) {      // 4 independent loads in flight
        const u64 a0 = part[base + (size_t)g * T_GT];
        const u64 a1 = part[base + (size_t)(g + 4) * T_GT];
        const u64 a2 = part[base + (size_t)(g + 8) * T_GT];
        const u64 a3 = part[base + (size_t)(g + 12) * T_GT];
        u64 x = a0 > a1 ? a0 : a1;
        const u64 y = a2 > a3 ? a2 : a3;
        if (y > x) x = y;
        if (x > m) m = x;
    }
    for (; g < NG; g += 4) {
        const u64 v = part[base + (size_t)g * T_GT];
        if (v > m) m = v;
    }
    s_best[w][t] = m;
    __syncthreads();
    if (tid < T_GT) {
        m = s_best[0][t];
        #pragma unroll
        for (int i = 1; i < 4; ++i) {
            const u64 v = s_best[i][t];
            if (v > m) m = v;
        }
        s_p[t] = 0xFFFFFFFFu - (u32)(m & 0xFFFFFFFFull);
    }
    __syncthreads();
    if (tid >= T_GT) return;

    // matches[best_prior] = arange(T): numpy last-wins on duplicates
    const u32 p = s_p[tid];
    for (int u = tid + 1; u < T_GT; ++u)
        if (s_p[u] == p) return;

    const float4 pr = priors[p];
    const float4 mb = s_gt[tid];
    const float  bcx = (mb.x + mb.z) * 0.5f;
    const float  bcy = (mb.y + mb.w) * 0.5f;
    const float  bw  = mb.z - mb.x;
    const float  bh  = mb.w - mb.y;

    const float lx = __fdividef(bcx - pr.x, 0.1f * pr.z);
    const float ly = __fdividef(bcy - pr.y, 0.1f * pr.w);
    const float lz = __logf(__fdividef(bw, pr.z)) * 5.0f;
    const float lw = __logf(__fdividef(bh, pr.w)) * 5.0f;

    float4* rowp = (float4*)(out_loc + ((size_t)b * P + p) * 4);
    *rowp = make_float4(lx, ly, lz, lw);
    out_lbl[(size_t)b * P + p] = (float)s_lbl[tid];
}

extern "C" void kernel_launch(void* const* d_in, const int* in_sizes, int n_in,
                              void* d_out, int out_size, void* d_ws, size_t ws_size,
                              hipStream_t stream) {
    const float4* priors    = (const float4*)d_in[0];   // (P, 4) f32
    const float4* gt_boxes  = (const float4*)d_in[1];   // (B, T, 4) f32
    const int*    gt_labels = (const int*)d_in[2];      // (B, T) i32

    const int P = in_sizes[0] / 4;
    const int B = in_sizes[2] / T_GT;

    float* out_loc = (float*)d_out;
    float* out_lbl = out_loc + (size_t)B * P * 4;

    const int NG = (P + TPB * KP - 1) / (TPB * KP);   // blocks per image (98)
    u64* part = (u64*)d_ws;                            // (B, NG, 64) u64

    dim3 g(NG, B);
    match_main<<<g, TPB, 0, stream>>>(priors, gt_boxes, gt_labels, part,
                                      out_loc, out_lbl, P, NG);
    match_fin<<<dim3(B), TPB, 0, stream>>>(priors, gt_boxes, gt_labels, part,
                                           out_loc, out_lbl, P, NG);
}